// Round 1
// baseline (12.854 us; speedup 1.0000x reference)
//
#include <hip/hip_runtime.h>

// BNN1D forward. Key observation: every bin_act in the reference is applied to
// a ReLU (or maxpool/mean of ReLU) output, which is exactly >= 0, and
// bsign(x>=0) = +1. So bin_act(h, s) == s everywhere and the network output is
// independent of x (and of stages 1-3 entirely). The exact forward reduces to:
//   alphaf = max|wf|; Sf[j] = sum_i sign(wf[j,i])
//   h4[j]  = sa3*alphaf*Sf[j] + bf[j]
//   r4[j]  = relu(BN4(h4[j]))
//   out[b,j] = sum_i r4[i]*wl[j,i] + bl[j]   (same for all b)

__global__ void bnn1d_const_forward(
    const float* __restrict__ wf,   // [64,128]
    const float* __restrict__ bf,   // [64]
    const float* __restrict__ g4,   // [64]
    const float* __restrict__ be4,  // [64]
    const float* __restrict__ m4,   // [64]
    const float* __restrict__ v4,   // [64]
    const float* __restrict__ wl,   // [10,64]
    const float* __restrict__ bl,   // [10]
    const float* __restrict__ sa3,  // scalar (1-elem array)
    float* __restrict__ out)        // [512,10]
{
    __shared__ float red[256];
    __shared__ float s_r4[64];
    __shared__ float s_out[10];
    const int t = threadIdx.x;

    // Phase 1: alphaf = max|wf| over 64*128 = 8192 elements
    float mx = 0.0f;
    for (int i = t; i < 64 * 128; i += 256) mx = fmaxf(mx, fabsf(wf[i]));
    red[t] = mx;
    __syncthreads();
    for (int s = 128; s > 0; s >>= 1) {
        if (t < s) red[t] = fmaxf(red[t], red[t + s]);
        __syncthreads();
    }
    const float alphaf = red[0];
    const float s3 = sa3[0];

    // Phase 2: per-output-channel binarized FC + BN4 + ReLU
    if (t < 64) {
        float sum = 0.0f;
        const float* row = wf + t * 128;
        #pragma unroll 8
        for (int i = 0; i < 128; ++i) sum += (row[i] >= 0.0f ? 1.0f : -1.0f);
        const float h4 = s3 * alphaf * sum + bf[t];
        const float z  = (h4 - m4[t]) * (g4[t] / sqrtf(v4[t] + 1e-5f)) + be4[t];
        s_r4[t] = fmaxf(z, 0.0f);
    }
    __syncthreads();

    // Phase 3: last_fc -> 10-vector
    if (t < 10) {
        float acc = bl[t];
        const float* row = wl + t * 64;
        #pragma unroll
        for (int i = 0; i < 64; ++i) acc += s_r4[i] * row[i];
        s_out[t] = acc;
    }
    __syncthreads();

    // Phase 4: broadcast to [512,10]
    for (int i = t; i < 512 * 10; i += 256) out[i] = s_out[i % 10];
}

extern "C" void kernel_launch(void* const* d_in, const int* in_sizes, int n_in,
                              void* d_out, int out_size, void* d_ws, size_t ws_size,
                              hipStream_t stream) {
    // setup_inputs() order:
    //  0:x 1:w1 2:b1 3:g1 4:be1 5:m1 6:v1
    //  7:w2 8:b2 9:g2 10:be2 11:m2 12:v2
    // 13:w3 14:b3 15:g3 16:be3 17:m3 18:v3
    // 19:wf 20:bf 21:g4 22:be4 23:m4 24:v4
    // 25:wl 26:bl 27:sa1 28:sa2 29:sa3
    const float* wf  = (const float*)d_in[19];
    const float* bf  = (const float*)d_in[20];
    const float* g4  = (const float*)d_in[21];
    const float* be4 = (const float*)d_in[22];
    const float* m4  = (const float*)d_in[23];
    const float* v4  = (const float*)d_in[24];
    const float* wl  = (const float*)d_in[25];
    const float* bl  = (const float*)d_in[26];
    const float* sa3 = (const float*)d_in[29];
    float* out = (float*)d_out;

    bnn1d_const_forward<<<1, 256, 0, stream>>>(wf, bf, g4, be4, m4, v4, wl, bl, sa3, out);
}

// Round 2
// 9.690 us; speedup vs baseline: 1.3265x; 1.3265x over previous
//
#include <hip/hip_runtime.h>

// BNN1D forward. Every bin_act in the reference is applied to a ReLU (or
// maxpool/mean of ReLU) output, which is exactly >= 0, and bsign(x>=0) = +1.
// So bin_act(h, s) == s everywhere and the network output is independent of x
// (and of stages 1-3 entirely). Exact forward:
//   alphaf = max|wf|; Sf[j] = sum_i sign(wf[j,i])
//   h4[j]  = sa3*alphaf*Sf[j] + bf[j]
//   r4[j]  = relu(BN4(h4[j]))
//   out[b,j] = sum_i r4[i]*wl[j,i] + bl[j]   (same for all b)
//
// Single block, 256 threads, single fused pass over wf (4 threads/row,
// float4 loads), vectorized float4 output broadcast.

__global__ void bnn1d_const_forward(
    const float* __restrict__ wf,   // [64,128]
    const float* __restrict__ bf,   // [64]
    const float* __restrict__ g4,   // [64]
    const float* __restrict__ be4,  // [64]
    const float* __restrict__ m4,   // [64]
    const float* __restrict__ v4,   // [64]
    const float* __restrict__ wl,   // [10,64]
    const float* __restrict__ bl,   // [10]
    const float* __restrict__ sa3,  // scalar (1-elem array)
    float* __restrict__ out)        // [512,10]
{
    __shared__ float s_wmax[4];
    __shared__ float s_r4[64];
    __shared__ float s_out[10];
    const int t = threadIdx.x;
    const int r = t >> 2;   // row 0..63
    const int q = t & 3;    // quarter of row

    // One pass over wf: per-thread absmax + per-row sign sum (32 elems each)
    const float4* w4 = reinterpret_cast<const float4*>(wf + r * 128 + q * 32);
    float mx = 0.0f, ssum = 0.0f;
    #pragma unroll
    for (int i = 0; i < 8; ++i) {
        float4 v = w4[i];
        mx = fmaxf(mx, fmaxf(fmaxf(fabsf(v.x), fabsf(v.y)),
                             fmaxf(fabsf(v.z), fabsf(v.w))));
        ssum += (v.x >= 0.f ? 1.f : -1.f) + (v.y >= 0.f ? 1.f : -1.f)
              + (v.z >= 0.f ? 1.f : -1.f) + (v.w >= 0.f ? 1.f : -1.f);
    }
    // sign-sum reduce across the 4 lanes of this row (lanes 4r..4r+3, same wave)
    ssum += __shfl_xor(ssum, 1);
    ssum += __shfl_xor(ssum, 2);
    // absmax reduce across the wave (exact: fmaxf is order-independent)
    #pragma unroll
    for (int off = 32; off >= 1; off >>= 1)
        mx = fmaxf(mx, __shfl_xor(mx, off));
    if ((t & 63) == 0) s_wmax[t >> 6] = mx;
    __syncthreads();
    const float alphaf = fmaxf(fmaxf(s_wmax[0], s_wmax[1]),
                               fmaxf(s_wmax[2], s_wmax[3]));

    // binarized FC + BN4 + ReLU (one lane per row)
    if (q == 0) {
        const float h4 = sa3[0] * alphaf * ssum + bf[r];
        const float z  = (h4 - m4[r]) * (g4[r] / sqrtf(v4[r] + 1e-5f)) + be4[r];
        s_r4[r] = fmaxf(z, 0.0f);
    }
    __syncthreads();

    // last_fc -> 10-vector
    if (t < 10) {
        float acc = bl[t];
        const float* row = wl + t * 64;
        #pragma unroll
        for (int i = 0; i < 64; ++i) acc += s_r4[i] * row[i];
        s_out[t] = acc;
    }
    __syncthreads();

    // broadcast to [512,10]: each thread writes rows 2t,2t+1 = 20 floats
    float o[10];
    #pragma unroll
    for (int i = 0; i < 10; ++i) o[i] = s_out[i];
    float4* dst = reinterpret_cast<float4*>(out + t * 20);
    dst[0] = make_float4(o[0], o[1], o[2], o[3]);
    dst[1] = make_float4(o[4], o[5], o[6], o[7]);
    dst[2] = make_float4(o[8], o[9], o[0], o[1]);
    dst[3] = make_float4(o[2], o[3], o[4], o[5]);
    dst[4] = make_float4(o[6], o[7], o[8], o[9]);
}

extern "C" void kernel_launch(void* const* d_in, const int* in_sizes, int n_in,
                              void* d_out, int out_size, void* d_ws, size_t ws_size,
                              hipStream_t stream) {
    // setup_inputs() order:
    //  0:x 1:w1 2:b1 3:g1 4:be1 5:m1 6:v1
    //  7:w2 8:b2 9:g2 10:be2 11:m2 12:v2
    // 13:w3 14:b3 15:g3 16:be3 17:m3 18:v3
    // 19:wf 20:bf 21:g4 22:be4 23:m4 24:v4
    // 25:wl 26:bl 27:sa1 28:sa2 29:sa3
    const float* wf  = (const float*)d_in[19];
    const float* bf  = (const float*)d_in[20];
    const float* g4  = (const float*)d_in[21];
    const float* be4 = (const float*)d_in[22];
    const float* m4  = (const float*)d_in[23];
    const float* v4  = (const float*)d_in[24];
    const float* wl  = (const float*)d_in[25];
    const float* bl  = (const float*)d_in[26];
    const float* sa3 = (const float*)d_in[29];
    float* out = (float*)d_out;

    bnn1d_const_forward<<<1, 256, 0, stream>>>(wf, bf, g4, be4, m4, v4, wl, bl, sa3, out);
}

// Round 3
// 9.674 us; speedup vs baseline: 1.3288x; 1.0017x over previous
//
#include <hip/hip_runtime.h>

// BNN1D forward. Every bin_act in the reference is applied to a ReLU (or
// maxpool/mean of ReLU) output, which is exactly >= 0, and bsign(x>=0) = +1.
// So bin_act(h, s) == s everywhere and the network output is independent of x
// (and of stages 1-3 entirely). Exact forward:
//   alphaf = max|wf|; Sf[j] = sum_i sign(wf[j,i])
//   h4[j]  = sa3*alphaf*Sf[j] + bf[j]
//   r4[j]  = relu(BN4(h4[j]))
//   out[b,j] = sum_i r4[i]*wl[j,i] + bl[j]   (same for all b)
//
// Single block, 256 threads. ALL global loads issued up front (one cold-load
// latency instead of three serialized ones); last_fc dot parallelized
// 10 rows x 16 lanes with shuffle reduce; float4 output broadcast.

__global__ void bnn1d_const_forward(
    const float* __restrict__ wf,   // [64,128]
    const float* __restrict__ bf,   // [64]
    const float* __restrict__ g4,   // [64]
    const float* __restrict__ be4,  // [64]
    const float* __restrict__ m4,   // [64]
    const float* __restrict__ v4,   // [64]
    const float* __restrict__ wl,   // [10,64]
    const float* __restrict__ bl,   // [10]
    const float* __restrict__ sa3,  // scalar (1-elem array)
    float* __restrict__ out)        // [512,10]
{
    __shared__ float s_wmax[4];
    __shared__ float s_r4[64];
    __shared__ float s_out[10];
    const int t = threadIdx.x;
    const int r = t >> 2;   // wf row 0..63
    const int q = t & 3;    // quarter of wf row
    const int j = t >> 4;   // wl row 0..15 (valid <10)
    const int l = t & 15;   // lane within wl row

    // ---- issue ALL independent global loads up front ----
    const float4* w4 = reinterpret_cast<const float4*>(wf + r * 128 + q * 32);
    float4 wv[8];
    #pragma unroll
    for (int i = 0; i < 8; ++i) wv[i] = w4[i];

    float p_bf = 0.f, p_m4 = 0.f, p_v4 = 1.f, p_g4 = 0.f, p_be4 = 0.f;
    if (q == 0) { p_bf = bf[r]; p_m4 = m4[r]; p_v4 = v4[r]; p_g4 = g4[r]; p_be4 = be4[r]; }
    const float s3 = sa3[0];

    float4 wlv = make_float4(0.f, 0.f, 0.f, 0.f);
    float p_bl = 0.f;
    if (t < 160) wlv = *reinterpret_cast<const float4*>(wl + j * 64 + l * 4);
    if (t < 10)  p_bl = bl[t];

    // ---- phase 1: absmax + per-row sign sums over wf ----
    float mx = 0.0f, ssum = 0.0f;
    #pragma unroll
    for (int i = 0; i < 8; ++i) {
        float4 v = wv[i];
        mx = fmaxf(mx, fmaxf(fmaxf(fabsf(v.x), fabsf(v.y)),
                             fmaxf(fabsf(v.z), fabsf(v.w))));
        ssum += (v.x >= 0.f ? 1.f : -1.f) + (v.y >= 0.f ? 1.f : -1.f)
              + (v.z >= 0.f ? 1.f : -1.f) + (v.w >= 0.f ? 1.f : -1.f);
    }
    ssum += __shfl_xor(ssum, 1);
    ssum += __shfl_xor(ssum, 2);
    #pragma unroll
    for (int off = 32; off >= 1; off >>= 1)
        mx = fmaxf(mx, __shfl_xor(mx, off));
    if ((t & 63) == 0) s_wmax[t >> 6] = mx;
    __syncthreads();
    const float alphaf = fmaxf(fmaxf(s_wmax[0], s_wmax[1]),
                               fmaxf(s_wmax[2], s_wmax[3]));

    // ---- phase 2: binarized FC + BN4 + ReLU ----
    if (q == 0) {
        const float h4 = s3 * alphaf * ssum + p_bf;
        const float z  = (h4 - p_m4) * (p_g4 / sqrtf(p_v4 + 1e-5f)) + p_be4;
        s_r4[r] = fmaxf(z, 0.0f);
    }
    __syncthreads();

    // ---- phase 3: last_fc, 16 lanes per output row ----
    if (t < 160) {
        const float4 rv = *reinterpret_cast<const float4*>(&s_r4[l * 4]);
        float p = rv.x * wlv.x + rv.y * wlv.y + rv.z * wlv.z + rv.w * wlv.w;
        p += __shfl_xor(p, 1);
        p += __shfl_xor(p, 2);
        p += __shfl_xor(p, 4);
        p += __shfl_xor(p, 8);
        if (l == 0) s_out[j] = p + bl[j];
    }
    __syncthreads();

    // ---- phase 4: broadcast to [512,10], 20 floats per thread ----
    float o[10];
    #pragma unroll
    for (int i = 0; i < 10; ++i) o[i] = s_out[i];
    float4* dst = reinterpret_cast<float4*>(out + t * 20);
    dst[0] = make_float4(o[0], o[1], o[2], o[3]);
    dst[1] = make_float4(o[4], o[5], o[6], o[7]);
    dst[2] = make_float4(o[8], o[9], o[0], o[1]);
    dst[3] = make_float4(o[2], o[3], o[4], o[5]);
    dst[4] = make_float4(o[6], o[7], o[8], o[9]);
}

extern "C" void kernel_launch(void* const* d_in, const int* in_sizes, int n_in,
                              void* d_out, int out_size, void* d_ws, size_t ws_size,
                              hipStream_t stream) {
    // setup_inputs() order:
    //  0:x 1:w1 2:b1 3:g1 4:be1 5:m1 6:v1
    //  7:w2 8:b2 9:g2 10:be2 11:m2 12:v2
    // 13:w3 14:b3 15:g3 16:be3 17:m3 18:v3
    // 19:wf 20:bf 21:g4 22:be4 23:m4 24:v4
    // 25:wl 26:bl 27:sa1 28:sa2 29:sa3
    const float* wf  = (const float*)d_in[19];
    const float* bf  = (const float*)d_in[20];
    const float* g4  = (const float*)d_in[21];
    const float* be4 = (const float*)d_in[22];
    const float* m4  = (const float*)d_in[23];
    const float* v4  = (const float*)d_in[24];
    const float* wl  = (const float*)d_in[25];
    const float* bl  = (const float*)d_in[26];
    const float* sa3 = (const float*)d_in[29];
    float* out = (float*)d_out;

    bnn1d_const_forward<<<1, 256, 0, stream>>>(wf, bf, g4, be4, m4, v4, wl, bl, sa3, out);
}